// Round 9
// baseline (358.583 us; speedup 1.0000x reference)
//
#include <hip/hip_runtime.h>
#include <hip/hip_fp16.h>
#include <cstddef>
#include <cstdint>

#define N_PTS 16384
#define K_PTS 1024
#define D_DIM 512
#define EPS_F 0.1f
#define ITERS 20
#define MU_F (1.0f/16384.0f)
#define NU_F (1.0f/1024.0f)
#define NCOPY 8
#define SINK_BLOCKS 256
#define FLAG_STRIDE 16   // 64B padding per flag
#define ACC_TOTAL ((ITERS + 1) * NCOPY * K_PTS)

// workspace: proven footprint only (~0.70 MB)
#define WS_ACCUM_BYTES ((size_t)ACC_TOTAL * 4)                    // 688128
#define WS_FLAGS_BYTES ((size_t)SINK_BLOCKS * FLAG_STRIDE * 4)    // 16384

// d_out layout (64 MiB + 4 B):
//   [0, 64 MiB)       T (final output)
//   [48 MiB, 49 MiB)  Pf16  } written by convert_p, read only in fused phase 1,
//   [49 MiB, +4 KiB)  pn    } clobbered by T only after 21 global flag barriers
//   [64 MiB]          loss

typedef float f32x4 __attribute__((ext_vector_type(4)));
typedef _Float16 f16x8 __attribute__((ext_vector_type(8)));

__device__ __forceinline__ float wave_reduce_sum(float s) {
#pragma unroll
  for (int off = 32; off > 0; off >>= 1) s += __shfl_xor(s, off, 64);
  return s;
}
__device__ __forceinline__ float wave_reduce_max(float s) {
#pragma unroll
  for (int off = 32; off > 0; off >>= 1) s = fmaxf(s, __shfl_xor(s, off, 64));
  return s;
}

// async 16B global->LDS (linear LDS dest: wave-uniform base + lane*16)
__device__ __forceinline__ void gl16(const void* g, void* l) {
  __builtin_amdgcn_global_load_lds(
      (const __attribute__((address_space(1))) unsigned int*)g,
      (__attribute__((address_space(3))) unsigned int*)l, 16, 0, 0);
}

// ---------------------------------------------------------------- init
__global__ __launch_bounds__(256) void init_kernel(float* __restrict__ accum,
                                                   unsigned int* __restrict__ flags,
                                                   unsigned int* __restrict__ maxbits,
                                                   float* __restrict__ loss) {
  int i = blockIdx.x * 256 + threadIdx.x;
  if (i < ACC_TOTAL) accum[i] = 0.0f;
  if (i < SINK_BLOCKS * FLAG_STRIDE) flags[i] = 0u;
  if (i == 0) { *maxbits = 0u; *loss = 0.0f; }
}

// ---------------------------------------------------------------- convert P only (3 MB total)
__global__ __launch_bounds__(256) void convert_p_kernel(const float* __restrict__ P,
                                                        unsigned short* __restrict__ Pf,
                                                        float* __restrict__ pn) {
  const int gw = (blockIdx.x * 256 + threadIdx.x) >> 6;  // row id 0..1023
  const int lane = threadIdx.x & 63;

  const float* src = P + (size_t)gw * D_DIM;
  unsigned short* dst = Pf + (size_t)gw * D_DIM;

  float4 f0 = *(const float4*)(src + lane * 8);
  float4 f1 = *(const float4*)(src + lane * 8 + 4);
  float f[8] = {f0.x, f0.y, f0.z, f0.w, f1.x, f1.y, f1.z, f1.w};

  float s = 0.f;
#pragma unroll
  for (int j = 0; j < 8; j++) s += f[j] * f[j];

  unsigned int u[4];
#pragma unroll
  for (int j = 0; j < 4; j++) {
    unsigned int lo = (unsigned int)__half_as_ushort(__float2half(f[2 * j]));
    unsigned int hi = (unsigned int)__half_as_ushort(__float2half(f[2 * j + 1]));
    u[j] = lo | (hi << 16);
  }
  *(uint4*)(dst + lane * 8) = make_uint4(u[0], u[1], u[2], u[3]);

  s = wave_reduce_sum(s);
  if (lane == 0) pn[gw] = s;
}

// ---------------------------------------------------------------- fused convert-X + GEMM + Sinkhorn
// 256 persistent blocks x 512 threads (1 block/CU). Phase 1: A (X-slab) MFMA
// fragments REGISTER-RESIDENT (16 x f16x8 = 64 VGPR), loaded directly from f32
// X with in-register f16 conversion + fused xn. C accumulated PACKED fp16
// (pk[64] u32 = 64 VGPR, not 128 f32) so peak register use stays < 256/wave
// at launch_bounds(512,2) — no spill (r8 post-mortem: areg pushed unified
// usage to ~300 -> scratch spill, suspected container kill). P streamed in
// 32-col panels through one 32KB buffer with register prefetch (r7-proven).
// Per-panel transpose tile t_lds (stride 36) feeds pk. One flags-round
// publishes global C max, then pk unpacks+exps into k4 (bit-identical values
// to r7's path); phase 2 = verified loop verbatim. Declared LDS ~46 KB.
__global__ __launch_bounds__(512, 2) void fused_kernel(
    const float* __restrict__ X,
    const unsigned short* __restrict__ Pf,
    const float* __restrict__ pn,
    unsigned int* __restrict__ maxbits,
    float* __restrict__ accum,          // (ITERS+1) x NCOPY x K_PTS
    unsigned int* __restrict__ flags,   // SINK_BLOCKS x FLAG_STRIDE
    float* __restrict__ T,
    float* __restrict__ loss) {
  __shared__ __align__(16) char smem[36864];               // Pbuf[32KB]; phase2: v_lds+red[36KB]
  __shared__ __align__(16) unsigned short t_lds[64 * 36];  // transpose tile, stride 36
  __shared__ float xn_s[64];
  __shared__ float pn_s[K_PTS];
  __shared__ float wred[8];

  unsigned short* Pbuf = (unsigned short*)smem;            // [32][512] halfs, granule-swizzled

  const int tid = threadIdx.x;
  const int lane = tid & 63, wv = tid >> 6;
  const int b = blockIdx.x;
  const int rb0 = b * 64;            // block's first row
  const int r0 = rb0 + wv * 8;       // wave's first owned row (phase-2 layout)

  // ---------------- phase 1a: P panel 0 (async) + A-fragment register preload ----------------
  // gl16 staging swizzle: LDS slot l holds source granule (l&~7)|((l&7)^(row&7)).
  const int gsw = (lane & ~7) | ((lane & 7) ^ (wv & 7));
#pragma unroll
  for (int q = 0; q < 4; q++) {
    int row = q * 8 + wv;            // row&7 == wv
    gl16((const char*)Pf + (size_t)row * 1024 + gsw * 16, Pbuf + row * 512);
  }

  const int rt = wv >> 1, ct = wv & 1;     // wave's row-tile (0..3), col-tile (0..1)
  const int fr = lane & 15, fg = lane >> 4;

  // A fragments: areg[kk] = X[rb0 + rt*16 + fr][kk*32 + fg*8 .. +8) as f16x8.
  f16x8 areg[16];
  float sxa = 0.f;
  {
    const float* xrow = X + (size_t)(rb0 + rt * 16 + fr) * D_DIM + fg * 8;
#pragma unroll
    for (int kk = 0; kk < 16; kk++) {
      float4 f0 = *(const float4*)(xrow + kk * 32);
      float4 f1 = *(const float4*)(xrow + kk * 32 + 4);
      float f[8] = {f0.x, f0.y, f0.z, f0.w, f1.x, f1.y, f1.z, f1.w};
      f16x8 a;
#pragma unroll
      for (int j = 0; j < 8; j++) {
        sxa += f[j] * f[j];
        a[j] = (_Float16)f[j];     // RTN, same as __float2half
      }
      areg[kk] = a;
    }
  }
  // row-norm: lane (fr,fg) holds 128 D-values of row rt*16+fr; reduce across fg lanes.
  sxa += __shfl_xor(sxa, 16, 64);
  sxa += __shfl_xor(sxa, 32, 64);
  if (lane < 16) xn_s[rt * 16 + lane] = sxa;   // both ct-waves of a rt write same bits (benign)

  pn_s[tid] = pn[tid];
  pn_s[tid + 512] = pn[tid + 512];
  __syncthreads();   // P panel 0 drained (vmcnt at barrier) + xn_s/pn_s visible

  // ---------------- phase 1b: 32 P panels ----------------
  // register-prefetch geometry: thread t handles panel row t>>4, granules (t&15)+16j
  const int prow = tid >> 4;          // 0..31
  const int pgl = tid & 15;

  float lmax = -3.4e38f;
  // packed C: pk[i*8 + q*2 + (e>>1)] holds halfs e&1=0 (lo16) / 1 (hi16)
  unsigned int pk[64];
#pragma unroll
  for (int j = 0; j < 64; j++) pk[j] = 0u;

#pragma unroll
  for (int p = 0; p < 32; p++) {
    // issue next panel's global loads early (latency hides under MFMA + barrier)
    uint4 pref[4];
    if (p < 31) {
      const char* srcrow = (const char*)Pf + (size_t)((p + 1) * 32 + prow) * 1024;
#pragma unroll
      for (int j = 0; j < 4; j++)
        pref[j] = *(const uint4*)(srcrow + (pgl + 16 * j) * 16);
    }

    f32x4 acc = {};
#pragma unroll
    for (int kk = 0; kk < 16; kk++) {
      int kg = kk * 4 + fg;
      int slot = (kg & ~7) | ((kg & 7) ^ (fr & 7));
      f16x8 bv = *(const f16x8*)&Pbuf[(ct * 16 + fr) * 512 + slot * 8];
      acc = __builtin_amdgcn_mfma_f32_16x16x32_f16(areg[kk], bv, acc, 0, 0, 0);
    }
    {  // tile epilogue: C/D layout col=lane&15, row=(lane>>4)*4+reg
      int colL = ct * 16 + fr;
      float pnc = pn_s[p * 32 + colL];
#pragma unroll
      for (int r = 0; r < 4; r++) {
        int rowL = rt * 16 + fg * 4 + r;
        float val = xn_s[rowL] + pnc - 2.0f * acc[r];
        lmax = fmaxf(lmax, val);   // f32 max before fp16 rounding (matches Ch path)
        t_lds[rowL * 36 + colL] = __half_as_ushort(__float2half(val));
      }
    }
    __syncthreads();   // B1: t_lds complete AND all Pbuf reads of panel p drained

    // commit prefetched panel p+1 into Pbuf (swizzled write = same involution as read)
    if (p < 31) {
#pragma unroll
      for (int j = 0; j < 4; j++) {
        int g = pgl + 16 * j;
        int slot = (g & ~7) | ((g & 7) ^ (prow & 7));
        *(uint4*)&Pbuf[prow * 512 + slot * 8] = pref[j];
      }
    }
    // extraction into packed registers: cols [32p,32p+32) belong to lanes with
    // lane>>5 == p&1; slot q=p>>3, e=(p>>1)&3 (all static under unroll)
    if ((lane >> 5) == (p & 1)) {
#pragma unroll
      for (int i = 0; i < 8; i++) {
        unsigned int h = t_lds[(wv * 8 + i) * 36 + (lane & 31)];
        const int q = p >> 3, e = (p >> 1) & 3;
        unsigned int w = pk[i * 8 + q * 2 + (e >> 1)];
        pk[i * 8 + q * 2 + (e >> 1)] =
            (e & 1) ? ((w & 0x0000FFFFu) | (h << 16))
                    : ((w & 0xFFFF0000u) | h);
      }
    }
    __syncthreads();   // B2: t_lds reusable + Pbuf write visible for next panel
  }

  // ---------------- global C-max round (flag value 1) ----------------
  lmax = wave_reduce_max(lmax);
  if (lane == 0) wred[wv] = lmax;
  __syncthreads();
  if (tid == 0) {
    float m = wred[0];
#pragma unroll
    for (int i = 1; i < 8; i++) m = fmaxf(m, wred[i]);
    atomicMax((int*)maxbits, __float_as_int(m));  // global max is positive
    __hip_atomic_store(&flags[(size_t)b * FLAG_STRIDE], 1u,
                       __ATOMIC_RELEASE, __HIP_MEMORY_SCOPE_AGENT);
  }
  if (tid < SINK_BLOCKS) {
    while (__hip_atomic_load(&flags[(size_t)tid * FLAG_STRIDE],
                             __ATOMIC_RELAXED, __HIP_MEMORY_SCOPE_AGENT) < 1u)
      __builtin_amdgcn_s_sleep(4);
  }
  __syncthreads();
  float factor;
  {
    float cmax = __uint_as_float(__hip_atomic_load(maxbits, __ATOMIC_RELAXED,
                                                   __HIP_MEMORY_SCOPE_AGENT));
    factor = -1.0f / ((cmax + 1e-8f) * EPS_F);
  }
  // unpack + exp: same fp16 values as r7's t_lds extraction -> bit-identical K
  f32x4 k4[32];
#pragma unroll
  for (int i = 0; i < 8; i++)
#pragma unroll
    for (int q = 0; q < 4; q++) {
      unsigned int w0 = pk[i * 8 + q * 2], w1 = pk[i * 8 + q * 2 + 1];
      f32x4 kk;
      kk[0] = __expf(__half2float(__ushort_as_half((unsigned short)(w0 & 0xFFFFu))) * factor);
      kk[1] = __expf(__half2float(__ushort_as_half((unsigned short)(w0 >> 16))) * factor);
      kk[2] = __expf(__half2float(__ushort_as_half((unsigned short)(w1 & 0xFFFFu))) * factor);
      kk[3] = __expf(__half2float(__ushort_as_half((unsigned short)(w1 >> 16))) * factor);
      k4[i * 4 + q] = kk;
    }

  // ---------------- phase 2: verified Sinkhorn loop (LDS aliases Pbuf region) ----------------
  float* v_lds = (float*)smem;                       // 4 KB
  float (*red)[K_PTS] = (float (*)[K_PTS])(smem + 4096);  // 8 x 4 KB
  v_lds[tid * 2 + 0] = 1.0f;
  v_lds[tid * 2 + 1] = 1.0f;
  __syncthreads();

  float su[8];
  for (int t = 0; t < ITERS; t++) {
    f32x4 vr4[4];
#pragma unroll
    for (int q = 0; q < 4; q++)
#pragma unroll
      for (int e = 0; e < 4; e++)
        vr4[q][e] = v_lds[(4 * q + e) * 64 + lane];

    float s[8];
#pragma unroll
    for (int i = 0; i < 8; i++) {
      f32x4 d = k4[i * 4 + 0] * vr4[0] + k4[i * 4 + 1] * vr4[1]
              + k4[i * 4 + 2] * vr4[2] + k4[i * 4 + 3] * vr4[3];
      s[i] = d[0] + d[1] + d[2] + d[3];
    }
    {
      const bool h32 = (lane & 32) != 0;
      float a[4];
#pragma unroll
      for (int i = 0; i < 4; i++) {
        float x = h32 ? s[i] : s[i + 4];
        float y = h32 ? s[i + 4] : s[i];
        a[i] = y + __shfl_xor(x, 32, 64);
      }
      const bool h16 = (lane & 16) != 0;
      float c[2];
#pragma unroll
      for (int i = 0; i < 2; i++) {
        float x = h16 ? a[i] : a[i + 2];
        float y = h16 ? a[i + 2] : a[i];
        c[i] = y + __shfl_xor(x, 16, 64);
      }
      const bool h8 = (lane & 8) != 0;
      float x = h8 ? c[0] : c[1];
      float y = h8 ? c[1] : c[0];
      float w = y + __shfl_xor(x, 8, 64);
      w += __shfl_xor(w, 4, 64);
      w += __shfl_xor(w, 2, 64);
      w += __shfl_xor(w, 1, 64);
      float ui_local = MU_F / (w + 1e-8f);
#pragma unroll
      for (int i = 0; i < 8; i++)
        su[i] = __uint_as_float(__builtin_amdgcn_readlane(__float_as_uint(ui_local), i * 8));
    }
    f32x4 ca4[4] = {};
#pragma unroll
    for (int i = 0; i < 8; i++)
#pragma unroll
      for (int q = 0; q < 4; q++)
        ca4[q] += su[i] * k4[i * 4 + q];

    __syncthreads();
#pragma unroll
    for (int q = 0; q < 4; q++)
#pragma unroll
      for (int e = 0; e < 4; e++)
        red[wv][(4 * q + e) * 64 + lane] = ca4[q][e];
    __syncthreads();
    {
      float s0 = 0.f, s1 = 0.f;
#pragma unroll
      for (int w8 = 0; w8 < 8; w8++) {
        float2 v2 = *(const float2*)&red[w8][tid * 2];
        s0 += v2.x; s1 += v2.y;
      }
      float* dst = accum + (size_t)(t + 1) * (NCOPY * K_PTS)
                 + (size_t)(b & (NCOPY - 1)) * K_PTS + tid * 2;
      atomicAdd(dst + 0, s0);
      atomicAdd(dst + 1, s1);
    }
    __syncthreads();
    if (tid == 0)
      __hip_atomic_store(&flags[(size_t)b * FLAG_STRIDE], (unsigned)(t + 2),
                         __ATOMIC_RELEASE, __HIP_MEMORY_SCOPE_AGENT);
    if (tid < SINK_BLOCKS) {
      while (__hip_atomic_load(&flags[(size_t)tid * FLAG_STRIDE],
                               __ATOMIC_RELAXED, __HIP_MEMORY_SCOPE_AGENT) < (unsigned)(t + 2))
        __builtin_amdgcn_s_sleep(4);
    }
    __syncthreads();
    {
      float* st = accum + (size_t)(t + 1) * (NCOPY * K_PTS);
      float s0 = 0.f, s1 = 0.f;
#pragma unroll
      for (int c = 0; c < NCOPY; c++) {  // agent-scope loads bypass stale caches (G16)
        s0 += __hip_atomic_load(st + (size_t)c * K_PTS + tid * 2 + 0,
                                __ATOMIC_RELAXED, __HIP_MEMORY_SCOPE_AGENT);
        s1 += __hip_atomic_load(st + (size_t)c * K_PTS + tid * 2 + 1,
                                __ATOMIC_RELAXED, __HIP_MEMORY_SCOPE_AGENT);
      }
      v_lds[tid * 2 + 0] = NU_F / (s0 + 1e-8f);
      v_lds[tid * 2 + 1] = NU_F / (s1 + 1e-8f);
    }
    __syncthreads();
  }

  // final: T = u*k*v from registers; loss = sum(T * (-eps*ln k)).
  float lsum = 0.f;
#pragma unroll
  for (int i = 0; i < 8; i++) {
    float* Trow = T + (size_t)(r0 + i) * K_PTS + lane;
#pragma unroll
    for (int q = 0; q < 4; q++) {
#pragma unroll
      for (int e = 0; e < 4; e++) {
        int c = (4 * q + e) * 64;
        float kk = k4[i * 4 + q][e];
        float tv = su[i] * kk * v_lds[c + lane];
        Trow[c] = tv;
        lsum += tv * (-EPS_F * __logf(kk));
      }
    }
  }
  lsum = wave_reduce_sum(lsum);
  __syncthreads();
  if (lane == 0) wred[wv] = lsum;
  __syncthreads();
  if (tid == 0) {
    float m = 0.f;
#pragma unroll
    for (int i = 0; i < 8; i++) m += wred[i];
    atomicAdd(loss, m);
  }
}

// ---------------------------------------------------------------- launcher
extern "C" void kernel_launch(void* const* d_in, const int* in_sizes, int n_in,
                              void* d_out, int out_size, void* d_ws, size_t ws_size,
                              hipStream_t stream) {
  const float* x = (const float*)d_in[0];
  const float* p = (const float*)d_in[1];
  float* T = (float*)d_out;
  float* loss = (float*)d_out + (size_t)N_PTS * K_PTS;

  // Pf16 + pn in d_out's upper half (clobbered only by final T writes,
  // which sit after 21 global flag barriers — all operand reads precede barrier 1)
  unsigned short* Pf = (unsigned short*)((char*)d_out + ((size_t)48 << 20));
  float* pn = (float*)((char*)d_out + ((size_t)49 << 20));

  char* wsb = (char*)d_ws;
  float* accum = (float*)wsb;
  unsigned int* flags = (unsigned int*)(wsb + WS_ACCUM_BYTES);
  unsigned int* maxbits = (unsigned int*)(wsb + WS_ACCUM_BYTES + WS_FLAGS_BYTES);

  init_kernel<<<(ACC_TOTAL + 255) / 256, 256, 0, stream>>>(accum, flags, maxbits, loss);
  convert_p_kernel<<<K_PTS / 4, 256, 0, stream>>>(p, Pf, pn);
  fused_kernel<<<SINK_BLOCKS, 512, 0, stream>>>(x, Pf, pn, maxbits, accum, flags, T, loss);
}

// Round 10
// 300.480 us; speedup vs baseline: 1.1934x; 1.1934x over previous
//
#include <hip/hip_runtime.h>
#include <hip/hip_fp16.h>
#include <cstddef>
#include <cstdint>

#define N_PTS 16384
#define K_PTS 1024
#define D_DIM 512
#define EPS_F 0.1f
#define ITERS 20
#define MU_F (1.0f/16384.0f)
#define NU_F (1.0f/1024.0f)
#define NCOPY 8
#define SINK_BLOCKS 256
#define FLAG_STRIDE 16   // 64B padding per flag
#define ACC_TOTAL ((ITERS + 1) * NCOPY * K_PTS)

// workspace: proven footprint only (~0.70 MB)
#define WS_ACCUM_BYTES ((size_t)ACC_TOTAL * 4)                    // 688128
#define WS_FLAGS_BYTES ((size_t)SINK_BLOCKS * FLAG_STRIDE * 4)    // 16384

// d_out layout (64 MiB + 4 B) — identical to r4 (session-best 299.7 µs):
//   [0,        32 MiB)  Ch    (fp16 C, staged between gemm and sinkhorn)
//   [32 MiB,   48 MiB)  Xf16  (f16 X, 16384x512)
//   [48 MiB,   49 MiB)  Pf16  (f16 P, 1024x512)
//   [49 MiB,  +64 KiB)  xn    (f32 row norms of X)
//   then       +4 KiB)  pn    (f32 row norms of P)
//   [64 MiB]            loss
// All regions are read before sinkhorn's final T writes clobber them.

typedef float f32x4 __attribute__((ext_vector_type(4)));
typedef _Float16 f16x8 __attribute__((ext_vector_type(8)));

__device__ __forceinline__ float wave_reduce_sum(float s) {
#pragma unroll
  for (int off = 32; off > 0; off >>= 1) s += __shfl_xor(s, off, 64);
  return s;
}
__device__ __forceinline__ float wave_reduce_max(float s) {
#pragma unroll
  for (int off = 32; off > 0; off >>= 1) s = fmaxf(s, __shfl_xor(s, off, 64));
  return s;
}

// async 16B global->LDS (linear LDS dest: wave-uniform base + lane*16)
__device__ __forceinline__ void gl16(const void* g, void* l) {
  __builtin_amdgcn_global_load_lds(
      (const __attribute__((address_space(1))) unsigned int*)g,
      (__attribute__((address_space(3))) unsigned int*)l, 16, 0, 0);
}

// ---------------------------------------------------------------- init + convert (merged: one launch)
// Grid 4352 x 256. Every block converts 4 rows (wave per row) of X|P to f16
// with fused exact-f32 row sum-of-squares (bit-identical to r4's convert).
// Blocks 0..671 additionally zero accum/flags (disjoint writes, no ordering
// needed within the kernel — everything completes before gemm launches).
__global__ __launch_bounds__(256) void init_conv_kernel(const float* __restrict__ X,
                                                        const float* __restrict__ P,
                                                        unsigned short* __restrict__ Xf,
                                                        unsigned short* __restrict__ Pf,
                                                        float* __restrict__ xn,
                                                        float* __restrict__ pn,
                                                        float* __restrict__ accum,
                                                        unsigned int* __restrict__ flags,
                                                        unsigned int* __restrict__ maxbits,
                                                        float* __restrict__ loss) {
  int i = blockIdx.x * 256 + threadIdx.x;
  if (i < ACC_TOTAL) accum[i] = 0.0f;
  if (i < SINK_BLOCKS * FLAG_STRIDE) flags[i] = 0u;
  if (i == 0) { *maxbits = 0u; *loss = 0.0f; }

  const int gw = i >> 6;  // global wave id = row id
  const int lane = threadIdx.x & 63;

  const float* src;
  unsigned short* dst;
  float* nrm;
  if (gw < N_PTS) {
    src = X + (size_t)gw * D_DIM;
    dst = Xf + (size_t)gw * D_DIM;
    nrm = xn + gw;
  } else {
    int r = gw - N_PTS;
    src = P + (size_t)r * D_DIM;
    dst = Pf + (size_t)r * D_DIM;
    nrm = pn + r;
  }

  float4 f0 = *(const float4*)(src + lane * 8);
  float4 f1 = *(const float4*)(src + lane * 8 + 4);
  float f[8] = {f0.x, f0.y, f0.z, f0.w, f1.x, f1.y, f1.z, f1.w};

  float s = 0.f;
#pragma unroll
  for (int j = 0; j < 8; j++) s += f[j] * f[j];

  unsigned int u[4];
#pragma unroll
  for (int j = 0; j < 4; j++) {
    unsigned int lo = (unsigned int)__half_as_ushort(__float2half(f[2 * j]));
    unsigned int hi = (unsigned int)__half_as_ushort(__float2half(f[2 * j + 1]));
    u[j] = lo | (hi << 16);
  }
  *(uint4*)(dst + lane * 8) = make_uint4(u[0], u[1], u[2], u[3]);

  s = wave_reduce_sum(s);
  if (lane == 0) *nrm = s;
}

// ---------------------------------------------------------------- f16 MFMA GEMM (verbatim r4, proven)
// C(fp16) = |x|^2 + |p|^2 - 2*x@p^T, single f16 MFMA term.
// 128x128 tile, BK=64 halfs, 8 K-iters, 2-stage double-buffered gl16 staging.
// Epilogue: fp16 tile through LDS (stride 272B), coalesced dwordx4 stores.
#define CT_STRIDE 136   // halfs per epilogue-tile row (272B = 17*16B)

__global__ __launch_bounds__(256, 2) void gemm4_kernel(const unsigned short* __restrict__ Xf,
                                                       const unsigned short* __restrict__ Pf,
                                                       const float* __restrict__ xn,
                                                       const float* __restrict__ pn,
                                                       __half* __restrict__ Ch,
                                                       unsigned int* __restrict__ maxbits) {
  __shared__ __align__(16) unsigned short Sh[2][2][128 * 64];   // 64 KB
  __shared__ float wmax[4];

  const int tid = threadIdx.x;
  const int lane = tid & 63, wv = tid >> 6;
  const int wm = wv >> 1, wn = wv & 1;
  const int m0 = blockIdx.y * 128, k0 = blockIdx.x * 128;

  const int srow = lane >> 3;
  const int sswg = ((lane & 7) ^ srow) << 4;        // swizzled source granule byte offset
  const char* gA = (const char*)(Xf + (size_t)m0 * D_DIM);
  const char* gB = (const char*)(Pf + (size_t)k0 * D_DIM);

  f32x4 acc[4][4] = {};

#define STAGE(buf, d0off)                                                         \
  do {                                                                            \
    _Pragma("unroll")                                                             \
    for (int is = 0; is < 4; is++) {                                              \
      const int chunk_ = wv * 4 + is;                                             \
      const size_t rb_ = (size_t)(chunk_ * 8 + srow) * (D_DIM * 2)                \
                       + (size_t)(d0off) * 2 + sswg;                              \
      gl16(gA + rb_, &Sh[buf][0][chunk_ * 512]);                                  \
      gl16(gB + rb_, &Sh[buf][1][chunk_ * 512]);                                  \
    }                                                                             \
  } while (0)

  STAGE(0, 0);
  __syncthreads();   // tile 0 resident

#pragma unroll
  for (int t = 0; t < 8; ++t) {
    const int cur = t & 1;
    if (t < 7) STAGE(cur ^ 1, (t + 1) * 64);   // prefetch next tile
    const unsigned short* Af = Sh[cur][0];
    const unsigned short* Bf = Sh[cur][1];

    f16x8 bv[2][4];
#pragma unroll
    for (int ks = 0; ks < 2; ks++)
#pragma unroll
      for (int ni = 0; ni < 4; ni++) {
        int rB = wn * 64 + ni * 16 + (lane & 15);
        int gBi = (ks * 4 + (lane >> 4)) ^ (rB & 7);
        bv[ks][ni] = *(const f16x8*)&Bf[rB * 64 + gBi * 8];
      }
#pragma unroll
    for (int mi = 0; mi < 4; mi++) {
      int rA = wm * 64 + mi * 16 + (lane & 15);
      int g0 = (0 + (lane >> 4)) ^ (rA & 7);
      int g1 = (4 + (lane >> 4)) ^ (rA & 7);
      f16x8 a0 = *(const f16x8*)&Af[rA * 64 + g0 * 8];
      f16x8 a1 = *(const f16x8*)&Af[rA * 64 + g1 * 8];
#pragma unroll
      for (int ni = 0; ni < 4; ni++) {
        acc[mi][ni] = __builtin_amdgcn_mfma_f32_16x16x32_f16(a0, bv[0][ni], acc[mi][ni], 0, 0, 0);
        acc[mi][ni] = __builtin_amdgcn_mfma_f32_16x16x32_f16(a1, bv[1][ni], acc[mi][ni], 0, 0, 0);
      }
    }
    __syncthreads();   // drains prefetch + this tile's ds_reads before buffer reuse
  }
#undef STAGE

  // epilogue: pack fp16 C-tile into LDS (stride 272B), then coalesced dwordx4 stores.
  unsigned short* Ct = &Sh[0][0][0];   // 128 * 136 halfs = 34,816 B, aliases staging
  float lmax = -3.4e38f;
#pragma unroll
  for (int mi = 0; mi < 4; mi++) {
    int rloc = wm * 64 + mi * 16 + (lane >> 4) * 4;
    float dxv[4];
#pragma unroll
    for (int r = 0; r < 4; r++) dxv[r] = xn[m0 + rloc + r];
#pragma unroll
    for (int ni = 0; ni < 4; ni++) {
      int cloc = wn * 64 + ni * 16 + (lane & 15);
      float pnc = pn[k0 + cloc];
#pragma unroll
      for (int r = 0; r < 4; r++) {
        float val = dxv[r] + pnc - 2.0f * acc[mi][ni][r];
        Ct[(rloc + r) * CT_STRIDE + cloc] = __half_as_ushort(__float2half(val));
        lmax = fmaxf(lmax, val);
      }
    }
  }
  __syncthreads();
#pragma unroll
  for (int j = 0; j < 8; j++) {
    int idx = j * 256 + tid;
    int row = idx >> 4, cq = idx & 15;
    uint4 v = *(const uint4*)&Ct[row * CT_STRIDE + cq * 8];
    *(uint4*)&Ch[(size_t)(m0 + row) * K_PTS + k0 + cq * 8] = v;
  }

  lmax = wave_reduce_max(lmax);
  if (lane == 0) wmax[wv] = lmax;
  __syncthreads();
  if (tid == 0) {
    float m = fmaxf(fmaxf(wmax[0], wmax[1]), fmaxf(wmax[2], wmax[3]));
    atomicMax((int*)maxbits, __float_as_int(m));  // global max is positive
  }
}

// ---------------------------------------------------------------- persistent Sinkhorn (verbatim r4, proven)
__global__ __launch_bounds__(512, 2) void sinkhorn_kernel(
    const __half* __restrict__ Ch,
    const unsigned int* __restrict__ maxbits,
    float* __restrict__ accum,          // (ITERS+1) x NCOPY x K_PTS
    unsigned int* __restrict__ flags,   // SINK_BLOCKS x FLAG_STRIDE
    float* __restrict__ T,
    float* __restrict__ loss) {
  __shared__ float v_lds[K_PTS];
  __shared__ float red[8][K_PTS];
  const int tid = threadIdx.x;
  const int lane = tid & 63, wv = tid >> 6;
  const int b = blockIdx.x;
  const int r0 = b * 64 + wv * 8;

  float factor;
  {
    float cmax = __int_as_float((int)*maxbits);
    factor = -1.0f / ((cmax + 1e-8f) * EPS_F);
  }
  f32x4 k4[32];
#pragma unroll
  for (int i = 0; i < 8; i++) {
    const __half* rp = Ch + (size_t)(r0 + i) * K_PTS + lane;
#pragma unroll
    for (int q = 0; q < 4; q++) {
      f32x4 kk;
#pragma unroll
      for (int e = 0; e < 4; e++)
        kk[e] = __expf(__half2float(rp[(4 * q + e) * 64]) * factor);
      k4[i * 4 + q] = kk;
    }
  }
  v_lds[tid * 2 + 0] = 1.0f;
  v_lds[tid * 2 + 1] = 1.0f;
  __syncthreads();

  float su[8];
  for (int t = 0; t < ITERS; t++) {
    f32x4 vr4[4];
#pragma unroll
    for (int q = 0; q < 4; q++)
#pragma unroll
      for (int e = 0; e < 4; e++)
        vr4[q][e] = v_lds[(4 * q + e) * 64 + lane];

    float s[8];
#pragma unroll
    for (int i = 0; i < 8; i++) {
      f32x4 d = k4[i * 4 + 0] * vr4[0] + k4[i * 4 + 1] * vr4[1]
              + k4[i * 4 + 2] * vr4[2] + k4[i * 4 + 3] * vr4[3];
      s[i] = d[0] + d[1] + d[2] + d[3];
    }
    {
      const bool h32 = (lane & 32) != 0;
      float a[4];
#pragma unroll
      for (int i = 0; i < 4; i++) {
        float x = h32 ? s[i] : s[i + 4];
        float y = h32 ? s[i + 4] : s[i];
        a[i] = y + __shfl_xor(x, 32, 64);
      }
      const bool h16 = (lane & 16) != 0;
      float c[2];
#pragma unroll
      for (int i = 0; i < 2; i++) {
        float x = h16 ? a[i] : a[i + 2];
        float y = h16 ? a[i + 2] : a[i];
        c[i] = y + __shfl_xor(x, 16, 64);
      }
      const bool h8 = (lane & 8) != 0;
      float x = h8 ? c[0] : c[1];
      float y = h8 ? c[1] : c[0];
      float w = y + __shfl_xor(x, 8, 64);
      w += __shfl_xor(w, 4, 64);
      w += __shfl_xor(w, 2, 64);
      w += __shfl_xor(w, 1, 64);
      float ui_local = MU_F / (w + 1e-8f);
#pragma unroll
      for (int i = 0; i < 8; i++)
        su[i] = __uint_as_float(__builtin_amdgcn_readlane(__float_as_uint(ui_local), i * 8));
    }
    f32x4 ca4[4] = {};
#pragma unroll
    for (int i = 0; i < 8; i++)
#pragma unroll
      for (int q = 0; q < 4; q++)
        ca4[q] += su[i] * k4[i * 4 + q];

    __syncthreads();
#pragma unroll
    for (int q = 0; q < 4; q++)
#pragma unroll
      for (int e = 0; e < 4; e++)
        red[wv][(4 * q + e) * 64 + lane] = ca4[q][e];
    __syncthreads();
    {
      float s0 = 0.f, s1 = 0.f;
#pragma unroll
      for (int w8 = 0; w8 < 8; w8++) {
        float2 v2 = *(const float2*)&red[w8][tid * 2];
        s0 += v2.x; s1 += v2.y;
      }
      float* dst = accum + (size_t)(t + 1) * (NCOPY * K_PTS)
                 + (size_t)(b & (NCOPY - 1)) * K_PTS + tid * 2;
      atomicAdd(dst + 0, s0);
      atomicAdd(dst + 1, s1);
    }
    __syncthreads();
    if (tid == 0)
      __hip_atomic_store(&flags[(size_t)b * FLAG_STRIDE], (unsigned)(t + 1),
                         __ATOMIC_RELEASE, __HIP_MEMORY_SCOPE_AGENT);
    if (tid < SINK_BLOCKS) {
      while (__hip_atomic_load(&flags[(size_t)tid * FLAG_STRIDE],
                               __ATOMIC_RELAXED, __HIP_MEMORY_SCOPE_AGENT) < (unsigned)(t + 1))
        __builtin_amdgcn_s_sleep(4);
    }
    __syncthreads();
    {
      float* st = accum + (size_t)(t + 1) * (NCOPY * K_PTS);
      float s0 = 0.f, s1 = 0.f;
#pragma unroll
      for (int c = 0; c < NCOPY; c++) {  // agent-scope loads bypass stale caches (G16)
        s0 += __hip_atomic_load(st + (size_t)c * K_PTS + tid * 2 + 0,
                                __ATOMIC_RELAXED, __HIP_MEMORY_SCOPE_AGENT);
        s1 += __hip_atomic_load(st + (size_t)c * K_PTS + tid * 2 + 1,
                                __ATOMIC_RELAXED, __HIP_MEMORY_SCOPE_AGENT);
      }
      v_lds[tid * 2 + 0] = NU_F / (s0 + 1e-8f);
      v_lds[tid * 2 + 1] = NU_F / (s1 + 1e-8f);
    }
    __syncthreads();
  }

  float lsum = 0.f;
#pragma unroll
  for (int i = 0; i < 8; i++) {
    float* Trow = T + (size_t)(r0 + i) * K_PTS + lane;
#pragma unroll
    for (int q = 0; q < 4; q++) {
#pragma unroll
      for (int e = 0; e < 4; e++) {
        int c = (4 * q + e) * 64;
        float kk = k4[i * 4 + q][e];
        float tv = su[i] * kk * v_lds[c + lane];
        Trow[c] = tv;
        lsum += tv * (-EPS_F * __logf(kk));
      }
    }
  }
  lsum = wave_reduce_sum(lsum);
  __shared__ float wsum[8];
  if (lane == 0) wsum[wv] = lsum;
  __syncthreads();
  if (tid == 0) {
    float m = 0.f;
#pragma unroll
    for (int i = 0; i < 8; i++) m += wsum[i];
    atomicAdd(loss, m);
  }
}

// ---------------------------------------------------------------- launcher (3 launches)
extern "C" void kernel_launch(void* const* d_in, const int* in_sizes, int n_in,
                              void* d_out, int out_size, void* d_ws, size_t ws_size,
                              hipStream_t stream) {
  const float* x = (const float*)d_in[0];
  const float* p = (const float*)d_in[1];
  float* T = (float*)d_out;
  float* loss = (float*)d_out + (size_t)N_PTS * K_PTS;
  __half* Ch = (__half*)d_out;  // fp16 C staged in d_out[0, 32MiB)

  // f16 operands + norms in d_out's upper half (dead until sinkhorn's final T write)
  unsigned short* Xf = (unsigned short*)((char*)d_out + ((size_t)32 << 20));
  unsigned short* Pf = (unsigned short*)((char*)d_out + ((size_t)48 << 20));
  float* xn = (float*)((char*)d_out + ((size_t)49 << 20));
  float* pn = xn + N_PTS;

  char* wsb = (char*)d_ws;
  float* accum = (float*)wsb;
  unsigned int* flags = (unsigned int*)(wsb + WS_ACCUM_BYTES);
  unsigned int* maxbits = (unsigned int*)(wsb + WS_ACCUM_BYTES + WS_FLAGS_BYTES);

  init_conv_kernel<<<(N_PTS + K_PTS) / 4, 256, 0, stream>>>(x, p, Xf, Pf, xn, pn,
                                                            accum, flags, maxbits, loss);
  gemm4_kernel<<<dim3(K_PTS / 128, N_PTS / 128), 256, 0, stream>>>(Xf, Pf, xn, pn, Ch, maxbits);
  sinkhorn_kernel<<<SINK_BLOCKS, 512, 0, stream>>>(Ch, maxbits, accum, flags, T, loss);
}

// Round 11
// 247.728 us; speedup vs baseline: 1.4475x; 1.2129x over previous
//
#include <hip/hip_runtime.h>
#include <hip/hip_fp16.h>
#include <cstddef>
#include <cstdint>

#define N_PTS 16384
#define K_PTS 1024
#define D_DIM 512
#define EPS_F 0.1f
#define ITERS 20
#define MU_F (1.0f/16384.0f)
#define NU_F (1.0f/1024.0f)
#define NCOPY 8
#define SINK_BLOCKS 256
#define FLAG_STRIDE 16   // 64B padding per flag
#define ACC_TOTAL ((ITERS + 1) * NCOPY * K_PTS)

// workspace: proven footprint only (~0.70 MB)
#define WS_ACCUM_BYTES ((size_t)ACC_TOTAL * 4)                    // 688128
#define WS_FLAGS_BYTES ((size_t)SINK_BLOCKS * FLAG_STRIDE * 4)    // 16384

// d_out layout (64 MiB + 4 B) — identical to r4/r10:
//   [0,        32 MiB)  Ch    (fp16 C, staged between gemm and sinkhorn)
//   [32 MiB,   48 MiB)  Xf16  (f16 X, 16384x512)
//   [48 MiB,   49 MiB)  Pf16  (f16 P, 1024x512)
//   [49 MiB,  +64 KiB)  xn    (f32 row norms of X)
//   then       +4 KiB)  pn    (f32 row norms of P)
//   [64 MiB]            loss
// All regions are read before sinkhorn's final T writes clobber them.

typedef float f32x4 __attribute__((ext_vector_type(4)));
typedef _Float16 f16x8 __attribute__((ext_vector_type(8)));

__device__ __forceinline__ float wave_reduce_sum(float s) {
#pragma unroll
  for (int off = 32; off > 0; off >>= 1) s += __shfl_xor(s, off, 64);
  return s;
}
__device__ __forceinline__ float wave_reduce_max(float s) {
#pragma unroll
  for (int off = 32; off > 0; off >>= 1) s = fmaxf(s, __shfl_xor(s, off, 64));
  return s;
}

// async 16B global->LDS (linear LDS dest: wave-uniform base + lane*16)
__device__ __forceinline__ void gl16(const void* g, void* l) {
  __builtin_amdgcn_global_load_lds(
      (const __attribute__((address_space(1))) unsigned int*)g,
      (__attribute__((address_space(3))) unsigned int*)l, 16, 0, 0);
}

// ---------------------------------------------------------------- init + convert (merged, proven r10)
__global__ __launch_bounds__(256) void init_conv_kernel(const float* __restrict__ X,
                                                        const float* __restrict__ P,
                                                        unsigned short* __restrict__ Xf,
                                                        unsigned short* __restrict__ Pf,
                                                        float* __restrict__ xn,
                                                        float* __restrict__ pn,
                                                        float* __restrict__ accum,
                                                        unsigned int* __restrict__ flags,
                                                        unsigned int* __restrict__ maxbits,
                                                        float* __restrict__ loss) {
  int i = blockIdx.x * 256 + threadIdx.x;
  if (i < ACC_TOTAL) accum[i] = 0.0f;
  if (i < SINK_BLOCKS * FLAG_STRIDE) flags[i] = 0u;
  if (i == 0) { *maxbits = 0u; *loss = 0.0f; }

  const int gw = i >> 6;  // global wave id = row id
  const int lane = threadIdx.x & 63;

  const float* src;
  unsigned short* dst;
  float* nrm;
  if (gw < N_PTS) {
    src = X + (size_t)gw * D_DIM;
    dst = Xf + (size_t)gw * D_DIM;
    nrm = xn + gw;
  } else {
    int r = gw - N_PTS;
    src = P + (size_t)r * D_DIM;
    dst = Pf + (size_t)r * D_DIM;
    nrm = pn + r;
  }

  float4 f0 = *(const float4*)(src + lane * 8);
  float4 f1 = *(const float4*)(src + lane * 8 + 4);
  float f[8] = {f0.x, f0.y, f0.z, f0.w, f1.x, f1.y, f1.z, f1.w};

  float s = 0.f;
#pragma unroll
  for (int j = 0; j < 8; j++) s += f[j] * f[j];

  unsigned int u[4];
#pragma unroll
  for (int j = 0; j < 4; j++) {
    unsigned int lo = (unsigned int)__half_as_ushort(__float2half(f[2 * j]));
    unsigned int hi = (unsigned int)__half_as_ushort(__float2half(f[2 * j + 1]));
    u[j] = lo | (hi << 16);
  }
  *(uint4*)(dst + lane * 8) = make_uint4(u[0], u[1], u[2], u[3]);

  s = wave_reduce_sum(s);
  if (lane == 0) *nrm = s;
}

// ---------------------------------------------------------------- f16 MFMA GEMM (verbatim r4/r10, proven)
#define CT_STRIDE 136   // halfs per epilogue-tile row (272B = 17*16B)

__global__ __launch_bounds__(256, 2) void gemm4_kernel(const unsigned short* __restrict__ Xf,
                                                       const unsigned short* __restrict__ Pf,
                                                       const float* __restrict__ xn,
                                                       const float* __restrict__ pn,
                                                       __half* __restrict__ Ch,
                                                       unsigned int* __restrict__ maxbits) {
  __shared__ __align__(16) unsigned short Sh[2][2][128 * 64];   // 64 KB
  __shared__ float wmax[4];

  const int tid = threadIdx.x;
  const int lane = tid & 63, wv = tid >> 6;
  const int wm = wv >> 1, wn = wv & 1;
  const int m0 = blockIdx.y * 128, k0 = blockIdx.x * 128;

  const int srow = lane >> 3;
  const int sswg = ((lane & 7) ^ srow) << 4;        // swizzled source granule byte offset
  const char* gA = (const char*)(Xf + (size_t)m0 * D_DIM);
  const char* gB = (const char*)(Pf + (size_t)k0 * D_DIM);

  f32x4 acc[4][4] = {};

#define STAGE(buf, d0off)                                                         \
  do {                                                                            \
    _Pragma("unroll")                                                             \
    for (int is = 0; is < 4; is++) {                                              \
      const int chunk_ = wv * 4 + is;                                             \
      const size_t rb_ = (size_t)(chunk_ * 8 + srow) * (D_DIM * 2)                \
                       + (size_t)(d0off) * 2 + sswg;                              \
      gl16(gA + rb_, &Sh[buf][0][chunk_ * 512]);                                  \
      gl16(gB + rb_, &Sh[buf][1][chunk_ * 512]);                                  \
    }                                                                             \
  } while (0)

  STAGE(0, 0);
  __syncthreads();   // tile 0 resident

#pragma unroll
  for (int t = 0; t < 8; ++t) {
    const int cur = t & 1;
    if (t < 7) STAGE(cur ^ 1, (t + 1) * 64);   // prefetch next tile
    const unsigned short* Af = Sh[cur][0];
    const unsigned short* Bf = Sh[cur][1];

    f16x8 bv[2][4];
#pragma unroll
    for (int ks = 0; ks < 2; ks++)
#pragma unroll
      for (int ni = 0; ni < 4; ni++) {
        int rB = wn * 64 + ni * 16 + (lane & 15);
        int gBi = (ks * 4 + (lane >> 4)) ^ (rB & 7);
        bv[ks][ni] = *(const f16x8*)&Bf[rB * 64 + gBi * 8];
      }
#pragma unroll
    for (int mi = 0; mi < 4; mi++) {
      int rA = wm * 64 + mi * 16 + (lane & 15);
      int g0 = (0 + (lane >> 4)) ^ (rA & 7);
      int g1 = (4 + (lane >> 4)) ^ (rA & 7);
      f16x8 a0 = *(const f16x8*)&Af[rA * 64 + g0 * 8];
      f16x8 a1 = *(const f16x8*)&Af[rA * 64 + g1 * 8];
#pragma unroll
      for (int ni = 0; ni < 4; ni++) {
        acc[mi][ni] = __builtin_amdgcn_mfma_f32_16x16x32_f16(a0, bv[0][ni], acc[mi][ni], 0, 0, 0);
        acc[mi][ni] = __builtin_amdgcn_mfma_f32_16x16x32_f16(a1, bv[1][ni], acc[mi][ni], 0, 0, 0);
      }
    }
    __syncthreads();   // drains prefetch + this tile's ds_reads before buffer reuse
  }
#undef STAGE

  // epilogue: pack fp16 C-tile into LDS (stride 272B), then coalesced dwordx4 stores.
  unsigned short* Ct = &Sh[0][0][0];   // 128 * 136 halfs = 34,816 B, aliases staging
  float lmax = -3.4e38f;
#pragma unroll
  for (int mi = 0; mi < 4; mi++) {
    int rloc = wm * 64 + mi * 16 + (lane >> 4) * 4;
    float dxv[4];
#pragma unroll
    for (int r = 0; r < 4; r++) dxv[r] = xn[m0 + rloc + r];
#pragma unroll
    for (int ni = 0; ni < 4; ni++) {
      int cloc = wn * 64 + ni * 16 + (lane & 15);
      float pnc = pn[k0 + cloc];
#pragma unroll
      for (int r = 0; r < 4; r++) {
        float val = dxv[r] + pnc - 2.0f * acc[mi][ni][r];
        Ct[(rloc + r) * CT_STRIDE + cloc] = __half_as_ushort(__float2half(val));
        lmax = fmaxf(lmax, val);
      }
    }
  }
  __syncthreads();
#pragma unroll
  for (int j = 0; j < 8; j++) {
    int idx = j * 256 + tid;
    int row = idx >> 4, cq = idx & 15;
    uint4 v = *(const uint4*)&Ct[row * CT_STRIDE + cq * 8];
    *(uint4*)&Ch[(size_t)(m0 + row) * K_PTS + k0 + cq * 8] = v;
  }

  lmax = wave_reduce_max(lmax);
  if (lane == 0) wmax[wv] = lmax;
  __syncthreads();
  if (tid == 0) {
    float m = fmaxf(fmaxf(wmax[0], wmax[1]), fmaxf(wmax[2], wmax[3]));
    atomicMax((int*)maxbits, __float_as_int(m));  // global max is positive
  }
}

// ---------------------------------------------------------------- persistent Sinkhorn
// r10-verbatim EXCEPT the flag store: RELEASE -> RELAXED.
// Justification: the preceding __syncthreads() compiles with s_waitcnt vmcnt(0)
// before s_barrier, so every agent-scope atomicAdd of this block has COMPLETED
// at the coherence point (L3) before any thread reaches the flag store. A
// relaxed flag store issued after cannot be observed before those completed
// adds; pollers read flag and accum with agent-scope (sc1) loads from the same
// coherence point. The RELEASE fence's conservative lowering (potential full
// L2 writeback per block per iteration) is therefore pure overhead.
__global__ __launch_bounds__(512, 2) void sinkhorn_kernel(
    const __half* __restrict__ Ch,
    const unsigned int* __restrict__ maxbits,
    float* __restrict__ accum,          // (ITERS+1) x NCOPY x K_PTS
    unsigned int* __restrict__ flags,   // SINK_BLOCKS x FLAG_STRIDE
    float* __restrict__ T,
    float* __restrict__ loss) {
  __shared__ float v_lds[K_PTS];
  __shared__ float red[8][K_PTS];
  const int tid = threadIdx.x;
  const int lane = tid & 63, wv = tid >> 6;
  const int b = blockIdx.x;
  const int r0 = b * 64 + wv * 8;

  float factor;
  {
    float cmax = __int_as_float((int)*maxbits);
    factor = -1.0f / ((cmax + 1e-8f) * EPS_F);
  }
  f32x4 k4[32];
#pragma unroll
  for (int i = 0; i < 8; i++) {
    const __half* rp = Ch + (size_t)(r0 + i) * K_PTS + lane;
#pragma unroll
    for (int q = 0; q < 4; q++) {
      f32x4 kk;
#pragma unroll
      for (int e = 0; e < 4; e++)
        kk[e] = __expf(__half2float(rp[(4 * q + e) * 64]) * factor);
      k4[i * 4 + q] = kk;
    }
  }
  v_lds[tid * 2 + 0] = 1.0f;
  v_lds[tid * 2 + 1] = 1.0f;
  __syncthreads();

  float su[8];
  for (int t = 0; t < ITERS; t++) {
    f32x4 vr4[4];
#pragma unroll
    for (int q = 0; q < 4; q++)
#pragma unroll
      for (int e = 0; e < 4; e++)
        vr4[q][e] = v_lds[(4 * q + e) * 64 + lane];

    float s[8];
#pragma unroll
    for (int i = 0; i < 8; i++) {
      f32x4 d = k4[i * 4 + 0] * vr4[0] + k4[i * 4 + 1] * vr4[1]
              + k4[i * 4 + 2] * vr4[2] + k4[i * 4 + 3] * vr4[3];
      s[i] = d[0] + d[1] + d[2] + d[3];
    }
    {
      const bool h32 = (lane & 32) != 0;
      float a[4];
#pragma unroll
      for (int i = 0; i < 4; i++) {
        float x = h32 ? s[i] : s[i + 4];
        float y = h32 ? s[i + 4] : s[i];
        a[i] = y + __shfl_xor(x, 32, 64);
      }
      const bool h16 = (lane & 16) != 0;
      float c[2];
#pragma unroll
      for (int i = 0; i < 2; i++) {
        float x = h16 ? a[i] : a[i + 2];
        float y = h16 ? a[i + 2] : a[i];
        c[i] = y + __shfl_xor(x, 16, 64);
      }
      const bool h8 = (lane & 8) != 0;
      float x = h8 ? c[0] : c[1];
      float y = h8 ? c[1] : c[0];
      float w = y + __shfl_xor(x, 8, 64);
      w += __shfl_xor(w, 4, 64);
      w += __shfl_xor(w, 2, 64);
      w += __shfl_xor(w, 1, 64);
      float ui_local = MU_F / (w + 1e-8f);
#pragma unroll
      for (int i = 0; i < 8; i++)
        su[i] = __uint_as_float(__builtin_amdgcn_readlane(__float_as_uint(ui_local), i * 8));
    }
    f32x4 ca4[4] = {};
#pragma unroll
    for (int i = 0; i < 8; i++)
#pragma unroll
      for (int q = 0; q < 4; q++)
        ca4[q] += su[i] * k4[i * 4 + q];

    __syncthreads();
#pragma unroll
    for (int q = 0; q < 4; q++)
#pragma unroll
      for (int e = 0; e < 4; e++)
        red[wv][(4 * q + e) * 64 + lane] = ca4[q][e];
    __syncthreads();
    {
      float s0 = 0.f, s1 = 0.f;
#pragma unroll
      for (int w8 = 0; w8 < 8; w8++) {
        float2 v2 = *(const float2*)&red[w8][tid * 2];
        s0 += v2.x; s1 += v2.y;
      }
      float* dst = accum + (size_t)(t + 1) * (NCOPY * K_PTS)
                 + (size_t)(b & (NCOPY - 1)) * K_PTS + tid * 2;
      atomicAdd(dst + 0, s0);
      atomicAdd(dst + 1, s1);
    }
    __syncthreads();  // s_waitcnt vmcnt(0) here => all this block's atomics completed at L3
    if (tid == 0)
      __hip_atomic_store(&flags[(size_t)b * FLAG_STRIDE], (unsigned)(t + 1),
                         __ATOMIC_RELAXED, __HIP_MEMORY_SCOPE_AGENT);  // was RELEASE (redundant fence)
    if (tid < SINK_BLOCKS) {
      while (__hip_atomic_load(&flags[(size_t)tid * FLAG_STRIDE],
                               __ATOMIC_RELAXED, __HIP_MEMORY_SCOPE_AGENT) < (unsigned)(t + 1))
        __builtin_amdgcn_s_sleep(4);
    }
    __syncthreads();
    {
      float* st = accum + (size_t)(t + 1) * (NCOPY * K_PTS);
      float s0 = 0.f, s1 = 0.f;
#pragma unroll
      for (int c = 0; c < NCOPY; c++) {  // agent-scope loads bypass stale caches (G16)
        s0 += __hip_atomic_load(st + (size_t)c * K_PTS + tid * 2 + 0,
                                __ATOMIC_RELAXED, __HIP_MEMORY_SCOPE_AGENT);
        s1 += __hip_atomic_load(st + (size_t)c * K_PTS + tid * 2 + 1,
                                __ATOMIC_RELAXED, __HIP_MEMORY_SCOPE_AGENT);
      }
      v_lds[tid * 2 + 0] = NU_F / (s0 + 1e-8f);
      v_lds[tid * 2 + 1] = NU_F / (s1 + 1e-8f);
    }
    __syncthreads();
  }

  float lsum = 0.f;
#pragma unroll
  for (int i = 0; i < 8; i++) {
    float* Trow = T + (size_t)(r0 + i) * K_PTS + lane;
#pragma unroll
    for (int q = 0; q < 4; q++) {
#pragma unroll
      for (int e = 0; e < 4; e++) {
        int c = (4 * q + e) * 64;
        float kk = k4[i * 4 + q][e];
        float tv = su[i] * kk * v_lds[c + lane];
        Trow[c] = tv;
        lsum += tv * (-EPS_F * __logf(kk));
      }
    }
  }
  lsum = wave_reduce_sum(lsum);
  __shared__ float wsum[8];
  if (lane == 0) wsum[wv] = lsum;
  __syncthreads();
  if (tid == 0) {
    float m = 0.f;
#pragma unroll
    for (int i = 0; i < 8; i++) m += wsum[i];
    atomicAdd(loss, m);
  }
}

// ---------------------------------------------------------------- launcher (3 launches)
extern "C" void kernel_launch(void* const* d_in, const int* in_sizes, int n_in,
                              void* d_out, int out_size, void* d_ws, size_t ws_size,
                              hipStream_t stream) {
  const float* x = (const float*)d_in[0];
  const float* p = (const float*)d_in[1];
  float* T = (float*)d_out;
  float* loss = (float*)d_out + (size_t)N_PTS * K_PTS;
  __half* Ch = (__half*)d_out;  // fp16 C staged in d_out[0, 32MiB)

  // f16 operands + norms in d_out's upper half (dead until sinkhorn's final T write)
  unsigned short* Xf = (unsigned short*)((char*)d_out + ((size_t)32 << 20));
  unsigned short* Pf = (unsigned short*)((char*)d_out + ((size_t)48 << 20));
  float* xn = (float*)((char*)d_out + ((size_t)49 << 20));
  float* pn = xn + N_PTS;

  char* wsb = (char*)d_ws;
  float* accum = (float*)wsb;
  unsigned int* flags = (unsigned int*)(wsb + WS_ACCUM_BYTES);
  unsigned int* maxbits = (unsigned int*)(wsb + WS_ACCUM_BYTES + WS_FLAGS_BYTES);

  init_conv_kernel<<<(N_PTS + K_PTS) / 4, 256, 0, stream>>>(x, p, Xf, Pf, xn, pn,
                                                            accum, flags, maxbits, loss);
  gemm4_kernel<<<dim3(K_PTS / 128, N_PTS / 128), 256, 0, stream>>>(Xf, Pf, xn, pn, Ch, maxbits);
  sinkhorn_kernel<<<SINK_BLOCKS, 512, 0, stream>>>(Ch, maxbits, accum, flags, T, loss);
}

// Round 12
// 244.174 us; speedup vs baseline: 1.4686x; 1.0146x over previous
//
#include <hip/hip_runtime.h>
#include <hip/hip_fp16.h>
#include <cstddef>
#include <cstdint>

#define N_PTS 16384
#define K_PTS 1024
#define D_DIM 512
#define EPS_F 0.1f
#define ITERS 20
#define MU_F (1.0f/16384.0f)
#define NU_F (1.0f/1024.0f)
#define NCOPY 8
#define SINK_BLOCKS 256
#define FLAG_STRIDE 16   // 64B padding per flag
#define ACC_TOTAL ((ITERS + 1) * NCOPY * K_PTS)

// workspace: proven footprint only (~0.70 MB)
#define WS_ACCUM_BYTES ((size_t)ACC_TOTAL * 4)                    // 688128
#define WS_FLAGS_BYTES ((size_t)SINK_BLOCKS * FLAG_STRIDE * 4)    // 16384

// d_out layout (64 MiB + 4 B) — identical to r4/r10/r11:
//   [0,        32 MiB)  Ch    (fp16 C, staged between gemm and sinkhorn)
//   [32 MiB,   48 MiB)  Xf16  (f16 X, 16384x512)
//   [48 MiB,   49 MiB)  Pf16  (f16 P, 1024x512)
//   [49 MiB,  +64 KiB)  xn    (f32 row norms of X)
//   then       +4 KiB)  pn    (f32 row norms of P)
//   [64 MiB]            loss
// All regions are read before sinkhorn's final T writes clobber them.

typedef float f32x4 __attribute__((ext_vector_type(4)));
typedef _Float16 f16x8 __attribute__((ext_vector_type(8)));

__device__ __forceinline__ float wave_reduce_sum(float s) {
#pragma unroll
  for (int off = 32; off > 0; off >>= 1) s += __shfl_xor(s, off, 64);
  return s;
}
__device__ __forceinline__ float wave_reduce_max(float s) {
#pragma unroll
  for (int off = 32; off > 0; off >>= 1) s = fmaxf(s, __shfl_xor(s, off, 64));
  return s;
}

// async 16B global->LDS (linear LDS dest: wave-uniform base + lane*16)
__device__ __forceinline__ void gl16(const void* g, void* l) {
  __builtin_amdgcn_global_load_lds(
      (const __attribute__((address_space(1))) unsigned int*)g,
      (__attribute__((address_space(3))) unsigned int*)l, 16, 0, 0);
}

// ---------------------------------------------------------------- init + convert (merged, proven r10/r11)
__global__ __launch_bounds__(256) void init_conv_kernel(const float* __restrict__ X,
                                                        const float* __restrict__ P,
                                                        unsigned short* __restrict__ Xf,
                                                        unsigned short* __restrict__ Pf,
                                                        float* __restrict__ xn,
                                                        float* __restrict__ pn,
                                                        float* __restrict__ accum,
                                                        unsigned int* __restrict__ flags,
                                                        unsigned int* __restrict__ maxbits,
                                                        float* __restrict__ loss) {
  int i = blockIdx.x * 256 + threadIdx.x;
  if (i < ACC_TOTAL) accum[i] = 0.0f;
  if (i < SINK_BLOCKS * FLAG_STRIDE) flags[i] = 0u;
  if (i == 0) { *maxbits = 0u; *loss = 0.0f; }

  const int gw = i >> 6;  // global wave id = row id
  const int lane = threadIdx.x & 63;

  const float* src;
  unsigned short* dst;
  float* nrm;
  if (gw < N_PTS) {
    src = X + (size_t)gw * D_DIM;
    dst = Xf + (size_t)gw * D_DIM;
    nrm = xn + gw;
  } else {
    int r = gw - N_PTS;
    src = P + (size_t)r * D_DIM;
    dst = Pf + (size_t)r * D_DIM;
    nrm = pn + r;
  }

  float4 f0 = *(const float4*)(src + lane * 8);
  float4 f1 = *(const float4*)(src + lane * 8 + 4);
  float f[8] = {f0.x, f0.y, f0.z, f0.w, f1.x, f1.y, f1.z, f1.w};

  float s = 0.f;
#pragma unroll
  for (int j = 0; j < 8; j++) s += f[j] * f[j];

  unsigned int u[4];
#pragma unroll
  for (int j = 0; j < 4; j++) {
    unsigned int lo = (unsigned int)__half_as_ushort(__float2half(f[2 * j]));
    unsigned int hi = (unsigned int)__half_as_ushort(__float2half(f[2 * j + 1]));
    u[j] = lo | (hi << 16);
  }
  *(uint4*)(dst + lane * 8) = make_uint4(u[0], u[1], u[2], u[3]);

  s = wave_reduce_sum(s);
  if (lane == 0) *nrm = s;
}

// ---------------------------------------------------------------- f16 MFMA GEMM (verbatim r4/r10/r11, proven)
#define CT_STRIDE 136   // halfs per epilogue-tile row (272B = 17*16B)

__global__ __launch_bounds__(256, 2) void gemm4_kernel(const unsigned short* __restrict__ Xf,
                                                       const unsigned short* __restrict__ Pf,
                                                       const float* __restrict__ xn,
                                                       const float* __restrict__ pn,
                                                       __half* __restrict__ Ch,
                                                       unsigned int* __restrict__ maxbits) {
  __shared__ __align__(16) unsigned short Sh[2][2][128 * 64];   // 64 KB
  __shared__ float wmax[4];

  const int tid = threadIdx.x;
  const int lane = tid & 63, wv = tid >> 6;
  const int wm = wv >> 1, wn = wv & 1;
  const int m0 = blockIdx.y * 128, k0 = blockIdx.x * 128;

  const int srow = lane >> 3;
  const int sswg = ((lane & 7) ^ srow) << 4;        // swizzled source granule byte offset
  const char* gA = (const char*)(Xf + (size_t)m0 * D_DIM);
  const char* gB = (const char*)(Pf + (size_t)k0 * D_DIM);

  f32x4 acc[4][4] = {};

#define STAGE(buf, d0off)                                                         \
  do {                                                                            \
    _Pragma("unroll")                                                             \
    for (int is = 0; is < 4; is++) {                                              \
      const int chunk_ = wv * 4 + is;                                             \
      const size_t rb_ = (size_t)(chunk_ * 8 + srow) * (D_DIM * 2)                \
                       + (size_t)(d0off) * 2 + sswg;                              \
      gl16(gA + rb_, &Sh[buf][0][chunk_ * 512]);                                  \
      gl16(gB + rb_, &Sh[buf][1][chunk_ * 512]);                                  \
    }                                                                             \
  } while (0)

  STAGE(0, 0);
  __syncthreads();   // tile 0 resident

#pragma unroll
  for (int t = 0; t < 8; ++t) {
    const int cur = t & 1;
    if (t < 7) STAGE(cur ^ 1, (t + 1) * 64);   // prefetch next tile
    const unsigned short* Af = Sh[cur][0];
    const unsigned short* Bf = Sh[cur][1];

    f16x8 bv[2][4];
#pragma unroll
    for (int ks = 0; ks < 2; ks++)
#pragma unroll
      for (int ni = 0; ni < 4; ni++) {
        int rB = wn * 64 + ni * 16 + (lane & 15);
        int gBi = (ks * 4 + (lane >> 4)) ^ (rB & 7);
        bv[ks][ni] = *(const f16x8*)&Bf[rB * 64 + gBi * 8];
      }
#pragma unroll
    for (int mi = 0; mi < 4; mi++) {
      int rA = wm * 64 + mi * 16 + (lane & 15);
      int g0 = (0 + (lane >> 4)) ^ (rA & 7);
      int g1 = (4 + (lane >> 4)) ^ (rA & 7);
      f16x8 a0 = *(const f16x8*)&Af[rA * 64 + g0 * 8];
      f16x8 a1 = *(const f16x8*)&Af[rA * 64 + g1 * 8];
#pragma unroll
      for (int ni = 0; ni < 4; ni++) {
        acc[mi][ni] = __builtin_amdgcn_mfma_f32_16x16x32_f16(a0, bv[0][ni], acc[mi][ni], 0, 0, 0);
        acc[mi][ni] = __builtin_amdgcn_mfma_f32_16x16x32_f16(a1, bv[1][ni], acc[mi][ni], 0, 0, 0);
      }
    }
    __syncthreads();   // drains prefetch + this tile's ds_reads before buffer reuse
  }
#undef STAGE

  // epilogue: pack fp16 C-tile into LDS (stride 272B), then coalesced dwordx4 stores.
  unsigned short* Ct = &Sh[0][0][0];   // 128 * 136 halfs = 34,816 B, aliases staging
  float lmax = -3.4e38f;
#pragma unroll
  for (int mi = 0; mi < 4; mi++) {
    int rloc = wm * 64 + mi * 16 + (lane >> 4) * 4;
    float dxv[4];
#pragma unroll
    for (int r = 0; r < 4; r++) dxv[r] = xn[m0 + rloc + r];
#pragma unroll
    for (int ni = 0; ni < 4; ni++) {
      int cloc = wn * 64 + ni * 16 + (lane & 15);
      float pnc = pn[k0 + cloc];
#pragma unroll
      for (int r = 0; r < 4; r++) {
        float val = dxv[r] + pnc - 2.0f * acc[mi][ni][r];
        Ct[(rloc + r) * CT_STRIDE + cloc] = __half_as_ushort(__float2half(val));
        lmax = fmaxf(lmax, val);
      }
    }
  }
  __syncthreads();
#pragma unroll
  for (int j = 0; j < 8; j++) {
    int idx = j * 256 + tid;
    int row = idx >> 4, cq = idx & 15;
    uint4 v = *(const uint4*)&Ct[row * CT_STRIDE + cq * 8];
    *(uint4*)&Ch[(size_t)(m0 + row) * K_PTS + k0 + cq * 8] = v;
  }

  lmax = wave_reduce_max(lmax);
  if (lane == 0) wmax[wv] = lmax;
  __syncthreads();
  if (tid == 0) {
    float m = fmaxf(fmaxf(wmax[0], wmax[1]), fmaxf(wmax[2], wmax[3]));
    atomicMax((int*)maxbits, __float_as_int(m));  // global max is positive
  }
}

// ---------------------------------------------------------------- persistent Sinkhorn
// r11-verbatim EXCEPT:
//  (1) Ch preamble vectorized: LDS-bounce through red[] (32KB = exactly 16 rows
//      x 1024 halfs), 4 chunks; cooperative dwordx4 loads replace 128 scalar
//      u16 loads/thread (8x fewer VMEM instructions; Ch is L3-resident so this
//      is issue-bound, not BW-bound). Same half values -> bit-identical k4.
//  (2) accum re-read uses 64-bit relaxed agent atomic loads (pairs fused).
__global__ __launch_bounds__(512, 2) void sinkhorn_kernel(
    const __half* __restrict__ Ch,
    const unsigned int* __restrict__ maxbits,
    float* __restrict__ accum,          // (ITERS+1) x NCOPY x K_PTS
    unsigned int* __restrict__ flags,   // SINK_BLOCKS x FLAG_STRIDE
    float* __restrict__ T,
    float* __restrict__ loss) {
  __shared__ float v_lds[K_PTS];
  __shared__ float red[8][K_PTS];
  const int tid = threadIdx.x;
  const int lane = tid & 63, wv = tid >> 6;
  const int b = blockIdx.x;
  const int r0 = b * 64 + wv * 8;

  float factor;
  {
    float cmax = __int_as_float((int)*maxbits);
    factor = -1.0f / ((cmax + 1e-8f) * EPS_F);
  }

  // ---- vectorized Ch preamble: bounce 16-row chunks through red[] ----
  f32x4 k4[32];
  {
    unsigned short* buf = (unsigned short*)red;   // 16 x 1024 halfs = 32 KB (exact)
    const unsigned short* Chu = (const unsigned short*)Ch;
    const int g_own = wv >> 1;                    // chunk holding this wave's rows
    const int lrow = (wv & 1) * 8;                // wave's first row within its chunk
#pragma unroll
    for (int g = 0; g < 4; g++) {
      // cooperative load of block rows [b*64 + g*16, +16): 2048 uint4, 4/thread
#pragma unroll
      for (int j = 0; j < 4; j++) {
        int idx = j * 512 + tid;        // 0..2047
        int row = idx >> 7;             // 0..15
        int c16 = idx & 127;            // uint4 index within row
        *(uint4*)&buf[row * 1024 + c16 * 8] =
            *(const uint4*)(Chu + (size_t)(b * 64 + g * 16 + row) * K_PTS + c16 * 8);
      }
      __syncthreads();
      if (g == g_own) {
#pragma unroll
        for (int i = 0; i < 8; i++)
#pragma unroll
          for (int q = 0; q < 4; q++) {
            f32x4 kk;
#pragma unroll
            for (int e = 0; e < 4; e++)
              kk[e] = __expf(__half2float(__ushort_as_half(
                          buf[(lrow + i) * 1024 + (4 * q + e) * 64 + lane])) * factor);
            k4[i * 4 + q] = kk;
          }
      }
      __syncthreads();   // buf reusable for next chunk
    }
  }
  v_lds[tid * 2 + 0] = 1.0f;
  v_lds[tid * 2 + 1] = 1.0f;
  __syncthreads();

  float su[8];
  for (int t = 0; t < ITERS; t++) {
    f32x4 vr4[4];
#pragma unroll
    for (int q = 0; q < 4; q++)
#pragma unroll
      for (int e = 0; e < 4; e++)
        vr4[q][e] = v_lds[(4 * q + e) * 64 + lane];

    float s[8];
#pragma unroll
    for (int i = 0; i < 8; i++) {
      f32x4 d = k4[i * 4 + 0] * vr4[0] + k4[i * 4 + 1] * vr4[1]
              + k4[i * 4 + 2] * vr4[2] + k4[i * 4 + 3] * vr4[3];
      s[i] = d[0] + d[1] + d[2] + d[3];
    }
    {
      const bool h32 = (lane & 32) != 0;
      float a[4];
#pragma unroll
      for (int i = 0; i < 4; i++) {
        float x = h32 ? s[i] : s[i + 4];
        float y = h32 ? s[i + 4] : s[i];
        a[i] = y + __shfl_xor(x, 32, 64);
      }
      const bool h16 = (lane & 16) != 0;
      float c[2];
#pragma unroll
      for (int i = 0; i < 2; i++) {
        float x = h16 ? a[i] : a[i + 2];
        float y = h16 ? a[i + 2] : a[i];
        c[i] = y + __shfl_xor(x, 16, 64);
      }
      const bool h8 = (lane & 8) != 0;
      float x = h8 ? c[0] : c[1];
      float y = h8 ? c[1] : c[0];
      float w = y + __shfl_xor(x, 8, 64);
      w += __shfl_xor(w, 4, 64);
      w += __shfl_xor(w, 2, 64);
      w += __shfl_xor(w, 1, 64);
      float ui_local = MU_F / (w + 1e-8f);
#pragma unroll
      for (int i = 0; i < 8; i++)
        su[i] = __uint_as_float(__builtin_amdgcn_readlane(__float_as_uint(ui_local), i * 8));
    }
    f32x4 ca4[4] = {};
#pragma unroll
    for (int i = 0; i < 8; i++)
#pragma unroll
      for (int q = 0; q < 4; q++)
        ca4[q] += su[i] * k4[i * 4 + q];

    __syncthreads();
#pragma unroll
    for (int q = 0; q < 4; q++)
#pragma unroll
      for (int e = 0; e < 4; e++)
        red[wv][(4 * q + e) * 64 + lane] = ca4[q][e];
    __syncthreads();
    {
      float s0 = 0.f, s1 = 0.f;
#pragma unroll
      for (int w8 = 0; w8 < 8; w8++) {
        float2 v2 = *(const float2*)&red[w8][tid * 2];
        s0 += v2.x; s1 += v2.y;
      }
      float* dst = accum + (size_t)(t + 1) * (NCOPY * K_PTS)
                 + (size_t)(b & (NCOPY - 1)) * K_PTS + tid * 2;
      atomicAdd(dst + 0, s0);
      atomicAdd(dst + 1, s1);
    }
    __syncthreads();  // s_waitcnt vmcnt(0) here => all this block's atomics completed at L3
    if (tid == 0)
      __hip_atomic_store(&flags[(size_t)b * FLAG_STRIDE], (unsigned)(t + 1),
                         __ATOMIC_RELAXED, __HIP_MEMORY_SCOPE_AGENT);  // relaxed (r11-proven)
    if (tid < SINK_BLOCKS) {
      while (__hip_atomic_load(&flags[(size_t)tid * FLAG_STRIDE],
                               __ATOMIC_RELAXED, __HIP_MEMORY_SCOPE_AGENT) < (unsigned)(t + 1))
        __builtin_amdgcn_s_sleep(4);
    }
    __syncthreads();
    {
      const float* st = accum + (size_t)(t + 1) * (NCOPY * K_PTS);
      float s0 = 0.f, s1 = 0.f;
#pragma unroll
      for (int c = 0; c < NCOPY; c++) {  // agent-scope 64-bit loads (pairs fused)
        unsigned long long v2 = __hip_atomic_load(
            (const unsigned long long*)(st + (size_t)c * K_PTS + tid * 2),
            __ATOMIC_RELAXED, __HIP_MEMORY_SCOPE_AGENT);
        s0 += __uint_as_float((unsigned int)(v2 & 0xFFFFFFFFull));
        s1 += __uint_as_float((unsigned int)(v2 >> 32));
      }
      v_lds[tid * 2 + 0] = NU_F / (s0 + 1e-8f);
      v_lds[tid * 2 + 1] = NU_F / (s1 + 1e-8f);
    }
    __syncthreads();
  }

  float lsum = 0.f;
#pragma unroll
  for (int i = 0; i < 8; i++) {
    float* Trow = T + (size_t)(r0 + i) * K_PTS + lane;
#pragma unroll
    for (int q = 0; q < 4; q++) {
#pragma unroll
      for (int e = 0; e < 4; e++) {
        int c = (4 * q + e) * 64;
        float kk = k4[i * 4 + q][e];
        float tv = su[i] * kk * v_lds[c + lane];
        Trow[c] = tv;
        lsum += tv * (-EPS_F * __logf(kk));
      }
    }
  }
  lsum = wave_reduce_sum(lsum);
  __shared__ float wsum[8];
  if (lane == 0) wsum[wv] = lsum;
  __syncthreads();
  if (tid == 0) {
    float m = 0.f;
#pragma unroll
    for (int i = 0; i < 8; i++) m += wsum[i];
    atomicAdd(loss, m);
  }
}

// ---------------------------------------------------------------- launcher (3 launches)
extern "C" void kernel_launch(void* const* d_in, const int* in_sizes, int n_in,
                              void* d_out, int out_size, void* d_ws, size_t ws_size,
                              hipStream_t stream) {
  const float* x = (const float*)d_in[0];
  const float* p = (const float*)d_in[1];
  float* T = (float*)d_out;
  float* loss = (float*)d_out + (size_t)N_PTS * K_PTS;
  __half* Ch = (__half*)d_out;  // fp16 C staged in d_out[0, 32MiB)

  // f16 operands + norms in d_out's upper half (dead until sinkhorn's final T write)
  unsigned short* Xf = (unsigned short*)((char*)d_out + ((size_t)32 << 20));
  unsigned short* Pf = (unsigned short*)((char*)d_out + ((size_t)48 << 20));
  float* xn = (float*)((char*)d_out + ((size_t)49 << 20));
  float* pn = xn + N_PTS;

  char* wsb = (char*)d_ws;
  float* accum = (float*)wsb;
  unsigned int* flags = (unsigned int*)(wsb + WS_ACCUM_BYTES);
  unsigned int* maxbits = (unsigned int*)(wsb + WS_ACCUM_BYTES + WS_FLAGS_BYTES);

  init_conv_kernel<<<(N_PTS + K_PTS) / 4, 256, 0, stream>>>(x, p, Xf, Pf, xn, pn,
                                                            accum, flags, maxbits, loss);
  gemm4_kernel<<<dim3(K_PTS / 128, N_PTS / 128), 256, 0, stream>>>(Xf, Pf, xn, pn, Ch, maxbits);
  sinkhorn_kernel<<<SINK_BLOCKS, 512, 0, stream>>>(Ch, maxbits, accum, flags, T, loss);
}